// Round 6
// baseline (184.204 us; speedup 1.0000x reference)
//
#include <hip/hip_runtime.h>
#include <math.h>

#define N_ATOMS 131072
#define N_MOLS  4096
#define DFEAT   128
#define NK      11
#define KDIM3   384          // 3 * DFEAT: [Sr | Sxr | Sxxr] blocks
#define N_DEPTH 128
#define EPS_F   1e-7f
#define MPB     8            // molecules per block (fused kernel)

__constant__ float c_means[NK] = {-1.645f, -1.08f, -0.739f, -0.468f, -0.228f,
                                  0.0f, 0.228f, 0.468f, 0.739f, 1.08f, 1.645f};
__constant__ float c_stds[NK]  = {0.283f, 0.17f, 0.134f, 0.118f, 0.114f,
                                  0.114f, 0.114f, 0.118f, 0.134f, 0.17f, 0.283f};

// Math (verified passing, rounds 2 & 5):
//   o_k(x) = 1 + a_k (x - m_k)^2,  a_k = 0.5 / (s_k^2 * log(s_k*sqrt(2pi))) < 0
//   den(x) = sum_k o_k + EPS = C2 x^2 + C1 x + C0   (always <= -178, rcp-safe)
//   (o_k+EPS)/den = coef0(k)*r + coef1(k)*(x r) + coef2(k)*(x^2 r),  r = 1/den
//   => segment sum needs only Sr, Sxr, Sxxr per (mol, feature);
//      W folds into Bt[384][128] once per launch.

// ---------------------------------------------------------------------------
// Kernel 1: (a) fold W into Bt[384][128]; (b) blocks >= 192 compute molecule
// offsets[0..4096] by binary search over the sorted atom_split.
// ---------------------------------------------------------------------------
__global__ __launch_bounds__(256) void wxform_offsets_kernel(
    const float* __restrict__ W,        // [DFEAT*NK, N_DEPTH]
    const int*   __restrict__ split,    // [N_ATOMS], sorted
    float*       __restrict__ Bt,       // [KDIM3, N_DEPTH]
    int*         __restrict__ offsets) {// [N_MOLS+1]
  const int bid = blockIdx.x;
  const int tid = threadIdx.x;
  if (bid < 192) {
    int t = bid * 256 + tid;            // 0..49151
    int n = t & 127;
    int row = t >> 7;                   // 0..383
    int j = row >> 7;                   // 0..2 (uniform per wave)
    int d = row & 127;
    float acc = 0.0f;
#pragma unroll
    for (int k = 0; k < NK; ++k) {
      float m = c_means[k], s = c_stds[k];
      float a = 0.5f / (s * s * logf(s * 2.5066282746310002f));
      float coef = (j == 2) ? a
                 : (j == 1) ? (-2.0f * a * m)
                            : fmaf(a, m * m, 1.0f + EPS_F);
      acc = fmaf(coef, W[(size_t)(d * NK + k) * N_DEPTH + n], acc);
    }
    Bt[(size_t)row * N_DEPTH + n] = acc;
  } else {
    int t = (bid - 192) * 256 + tid;    // 0..4351
    if (t <= N_MOLS) {
      int lo = 0, hi = N_ATOMS;
      while (lo < hi) { int mid = (lo + hi) >> 1; if (split[mid] < t) lo = mid + 1; else hi = mid; }
      offsets[t] = lo;
    }
  }
}

// ---------------------------------------------------------------------------
// Kernel 2 (fused): per block, MPB=8 molecules.
// Phase A (flattened): the block's 8 molecules are a contiguous atom range
//   [offs[0], offs[8]). 8 atom-groups x 32 feature-quads stride the WHOLE
//   range (no per-molecule remainder waste); each atom is classified into
//   its molecule (7 comparisons, uniform per 32-lane group) and accumulated
//   into statically-indexed acc[8][12] via an unrolled predicated select.
//   x loads: float4/lane, 2 in flight (explicit x2 unroll) -> 16 KB/CU
//   outstanding at 8 waves/CU > the 9.4 KB needed for full HBM draw.
// Phase B: out rows = tanh(As @ Bt + b); each Bt element read exactly once
//   per block. MPB=8 halves total Bt L2 traffic vs MPB=4 (201->100 MB).
// ---------------------------------------------------------------------------
__global__ __launch_bounds__(256, 2) void fused_sums_gemm_kernel(
    const float* __restrict__ x,        // [N_ATOMS, DFEAT]
    const int*   __restrict__ offsets,  // [N_MOLS+1]
    const float* __restrict__ Bt,       // [KDIM3, N_DEPTH]
    const float* __restrict__ bias,     // [N_DEPTH]
    float*       __restrict__ out) {    // [N_MOLS, N_DEPTH]
  const int tid = threadIdx.x;
  const int m0  = blockIdx.x * MPB;

  __shared__ float As[MPB][KDIM3];      // 12 KB, persists through phase B
  __shared__ float red[8][32][13];      // 13.3 KB, reused as comb in phase B
  float (*comb)[MPB][DFEAT] = (float (*)[MPB][DFEAT])red;  // [2][8][128]

  // Horner coefficients for den = sum_k o_k + EPS (uniform, tiny)
  float C2 = 0.0f, C1 = 0.0f, C0 = 11.0f + EPS_F;
#pragma unroll
  for (int k = 0; k < NK; ++k) {
    float m_ = c_means[k], s_ = c_stds[k];
    float a = 0.5f / (s_ * s_ * logf(s_ * 2.5066282746310002f));
    C2 += a;
    C1 = fmaf(-2.0f * a, m_, C1);
    C0 = fmaf(a, m_ * m_, C0);
  }

  int offs[MPB + 1];
#pragma unroll
  for (int i = 0; i <= MPB; ++i) offs[i] = offsets[m0 + i];

  const int fq = tid & 31;              // feature quad: features fq*4..fq*4+3
  const int g  = tid >> 5;              // atom group 0..7

  float acc[MPB][12];                   // [mol][3*q + {Sr,Sxr,Sxxr}]
#pragma unroll
  for (int i = 0; i < MPB; ++i)
#pragma unroll
    for (int j = 0; j < 12; ++j) acc[i][j] = 0.0f;

  const int base = offs[0], endA = offs[MPB];

  auto proc = [&](float4 v, int a) {
    float xv[4] = {v.x, v.y, v.z, v.w};
    float rr[4], uu[4];
#pragma unroll
    for (int q = 0; q < 4; ++q) {
      float den = fmaf(fmaf(C2, xv[q], C1), xv[q], C0);
      rr[q] = __builtin_amdgcn_rcpf(den);   // den <= -178 always
      uu[q] = xv[q] * rr[q];
    }
    int mid = 0;
#pragma unroll
    for (int j = 1; j < MPB; ++j) mid += (a >= offs[j]) ? 1 : 0;
#pragma unroll
    for (int i = 0; i < MPB; ++i)
      if (mid == i) {                   // uniform per 32-lane group
#pragma unroll
        for (int q = 0; q < 4; ++q) {
          acc[i][3 * q + 0] += rr[q];
          acc[i][3 * q + 1] += uu[q];
          acc[i][3 * q + 2] = fmaf(xv[q], uu[q], acc[i][3 * q + 2]);
        }
      }
  };

  // ---------------- Phase A: flattened segment sums ----------------
  int a = base + g;
  for (; a + 8 < endA; a += 16) {       // x2 unroll: 2 loads in flight
    float4 v0 = *(const float4*)&x[(size_t)a * DFEAT + fq * 4];
    float4 v1 = *(const float4*)&x[(size_t)(a + 8) * DFEAT + fq * 4];
    proc(v0, a);
    proc(v1, a + 8);
  }
  if (a < endA) {
    float4 v = *(const float4*)&x[(size_t)a * DFEAT + fq * 4];
    proc(v, a);
  }

  // Per-molecule cross-group reduction (red reused each round)
#pragma unroll
  for (int i = 0; i < MPB; ++i) {
#pragma unroll
    for (int j = 0; j < 12; ++j) red[g][fq][j] = acc[i][j];
    __syncthreads();
    for (int t = tid; t < KDIM3; t += 256) {
      int comp = t >> 7;                // 0:Sr 1:Sxr 2:Sxxr
      int f = t & 127;
      int q = f >> 2, fi = f & 3;
      float s = 0.0f;
#pragma unroll
      for (int gg = 0; gg < 8; ++gg) s += red[gg][q][fi * 3 + comp];
      As[i][t] = s;
    }
    __syncthreads();
  }

  // ---------------- Phase B: [8 x 384] @ Bt[384 x 128] ----------------
  const int n = tid & 127;              // output column
  const int h = tid >> 7;               // k-half 0/1 (uniform per wave)
  const int kbase = h * (KDIM3 / 2);    // 0 or 192

  float pacc[MPB];
#pragma unroll
  for (int i = 0; i < MPB; ++i) pacc[i] = 0.0f;

#pragma unroll 2
  for (int kk = 0; kk < KDIM3 / 2; kk += 4) {
    int k = kbase + kk;
    float b0 = Bt[(size_t)(k + 0) * N_DEPTH + n];
    float b1 = Bt[(size_t)(k + 1) * N_DEPTH + n];
    float b2 = Bt[(size_t)(k + 2) * N_DEPTH + n];
    float b3 = Bt[(size_t)(k + 3) * N_DEPTH + n];
#pragma unroll
    for (int i = 0; i < MPB; ++i) {
      float4 av = *(const float4*)&As[i][k];   // wave-uniform -> LDS broadcast
      pacc[i] = fmaf(av.x, b0, pacc[i]);
      pacc[i] = fmaf(av.y, b1, pacc[i]);
      pacc[i] = fmaf(av.z, b2, pacc[i]);
      pacc[i] = fmaf(av.w, b3, pacc[i]);
    }
  }

  // Combine the two k-halves via LDS (aliases red; all red reads are done).
#pragma unroll
  for (int i = 0; i < MPB; ++i) comb[h][i][n] = pacc[i];
  __syncthreads();

#pragma unroll
  for (int off = 0; off < (MPB * DFEAT) / 256; ++off) {  // 4 iters
    int idx = off * 256 + tid;
    int i  = idx >> 7;
    int nn = idx & 127;
    float v = comb[0][i][nn] + comb[1][i][nn] + bias[nn];
    out[(size_t)(m0 + i) * N_DEPTH + nn] = tanhf(v);
  }
}

// ---------------------------------------------------------------------------
extern "C" void kernel_launch(void* const* d_in, const int* in_sizes, int n_in,
                              void* d_out, int out_size, void* d_ws, size_t ws_size,
                              hipStream_t stream) {
  const float* x     = (const float*)d_in[0];  // [131072, 128] f32
  const int*   split = (const int*)d_in[1];    // [131072] int (sorted)
  const float* W     = (const float*)d_in[2];  // [1408, 128] f32
  const float* bias  = (const float*)d_in[3];  // [128] f32
  float* out = (float*)d_out;                  // [4096, 128] f32

  // Workspace: Bt[384*128] f32 then offsets[4097] int (~213 KB total)
  float* Bt      = (float*)d_ws;
  int*   offsets = (int*)((char*)d_ws + (size_t)KDIM3 * N_DEPTH * 4);

  wxform_offsets_kernel<<<dim3(192 + 17), dim3(256), 0, stream>>>(W, split, Bt, offsets);
  fused_sums_gemm_kernel<<<dim3(N_MOLS / MPB), dim3(256), 0, stream>>>(x, offsets, Bt, bias, out);
}

// Round 7
// 113.356 us; speedup vs baseline: 1.6250x; 1.6250x over previous
//
#include <hip/hip_runtime.h>
#include <math.h>

#define N_ATOMS 131072
#define N_MOLS  4096
#define DFEAT   128
#define NK      11
#define KDIM3   384          // 3 * DFEAT: [Sr | Sxr | Sxxr] blocks
#define N_DEPTH 128
#define EPS_F   1e-7f
#define MPB     8            // molecules per block = waves per block
#define TPB     512

__constant__ float c_means[NK] = {-1.645f, -1.08f, -0.739f, -0.468f, -0.228f,
                                  0.0f, 0.228f, 0.468f, 0.739f, 1.08f, 1.645f};
__constant__ float c_stds[NK]  = {0.283f, 0.17f, 0.134f, 0.118f, 0.114f,
                                  0.114f, 0.114f, 0.118f, 0.134f, 0.17f, 0.283f};

// Math (verified passing, rounds 2 & 5):
//   o_k(x) = 1 + a_k (x - m_k)^2,  a_k = 0.5 / (s_k^2 * log(s_k*sqrt(2pi))) < 0
//   den(x) = sum_k o_k + EPS = C2 x^2 + C1 x + C0   (always <= -178, rcp-safe)
//   (o_k+EPS)/den = coef0(k)*r + coef1(k)*(x r) + coef2(k)*(x^2 r),  r = 1/den
//   => segment sum needs only Sr, Sxr, Sxxr per (mol, feature);
//      W folds into Bt[384][128] once per launch.

// ---------------------------------------------------------------------------
// Kernel 1: (a) fold W into Bt[384][128]; (b) blocks >= 192 compute molecule
// offsets[0..4096] by binary search over the sorted atom_split.
// ---------------------------------------------------------------------------
__global__ __launch_bounds__(256) void wxform_offsets_kernel(
    const float* __restrict__ W,        // [DFEAT*NK, N_DEPTH]
    const int*   __restrict__ split,    // [N_ATOMS], sorted
    float*       __restrict__ Bt,       // [KDIM3, N_DEPTH]
    int*         __restrict__ offsets) {// [N_MOLS+1]
  const int bid = blockIdx.x;
  const int tid = threadIdx.x;
  if (bid < 192) {
    int t = bid * 256 + tid;            // 0..49151
    int n = t & 127;
    int row = t >> 7;                   // 0..383
    int j = row >> 7;                   // 0..2 (uniform per wave)
    int d = row & 127;
    float acc = 0.0f;
#pragma unroll
    for (int k = 0; k < NK; ++k) {
      float m = c_means[k], s = c_stds[k];
      float a = 0.5f / (s * s * logf(s * 2.5066282746310002f));
      float coef = (j == 2) ? a
                 : (j == 1) ? (-2.0f * a * m)
                            : fmaf(a, m * m, 1.0f + EPS_F);
      acc = fmaf(coef, W[(size_t)(d * NK + k) * N_DEPTH + n], acc);
    }
    Bt[(size_t)row * N_DEPTH + n] = acc;
  } else {
    int t = (bid - 192) * 256 + tid;    // 0..4351
    if (t <= N_MOLS) {
      int lo = 0, hi = N_ATOMS;
      while (lo < hi) { int mid = (lo + hi) >> 1; if (split[mid] < t) lo = mid + 1; else hi = mid; }
      offsets[t] = lo;
    }
  }
}

// ---------------------------------------------------------------------------
// Kernel 2 (fused): 512 threads = 8 waves; wave w owns molecule m0+w.
// Phase A: lanes 0-31 process even atoms, 32-63 odd atoms (one wave load =
//   2 contiguous x-rows = 1 KB, fully coalesced). 12 register accumulators
//   per lane; cross-half combine is 12 x shfl_xor(32) in-register.
//   NO barriers, NO LDS reduce, NO spill (key fix vs round 6).
// Phase B: [8 x 384] @ Bt[384 x 128], 4-way k-split; each Bt element read
//   exactly once per block (512 blocks x 196 KB = 100 MB L2-resident).
// ---------------------------------------------------------------------------
__global__ __launch_bounds__(TPB) void fused_sums_gemm_kernel(
    const float* __restrict__ x,        // [N_ATOMS, DFEAT]
    const int*   __restrict__ offsets,  // [N_MOLS+1]
    const float* __restrict__ Bt,       // [KDIM3, N_DEPTH]
    const float* __restrict__ bias,     // [N_DEPTH]
    float*       __restrict__ out) {    // [N_MOLS, N_DEPTH]
  const int tid = threadIdx.x;
  const int m0  = blockIdx.x * MPB;

  __shared__ float As[MPB][KDIM3];      // 12 KB
  __shared__ float comb[4][MPB][DFEAT]; // 16 KB

  // Horner coefficients for den = sum_k o_k + EPS (uniform, tiny)
  float C2 = 0.0f, C1 = 0.0f, C0 = 11.0f + EPS_F;
#pragma unroll
  for (int k = 0; k < NK; ++k) {
    float m_ = c_means[k], s_ = c_stds[k];
    float a = 0.5f / (s_ * s_ * logf(s_ * 2.5066282746310002f));
    C2 += a;
    C1 = fmaf(-2.0f * a, m_, C1);
    C0 = fmaf(a, m_ * m_, C0);
  }

  const int w    = tid >> 6;            // wave id = molecule slot 0..7
  const int lane = tid & 63;
  const int fq   = lane & 31;           // feature quad: features fq*4..fq*4+3
  const int h    = lane >> 5;           // atom parity 0/1

  const int start = offsets[m0 + w];
  const int end   = offsets[m0 + w + 1];

  // ---------------- Phase A: per-wave molecule sums ----------------
  float Sr[4]   = {0.f, 0.f, 0.f, 0.f};
  float Sxr[4]  = {0.f, 0.f, 0.f, 0.f};
  float Sxxr[4] = {0.f, 0.f, 0.f, 0.f};

  int a = start + h;
  // x2 unroll: 2 wave-loads (2 KB) in flight
  for (; a + 2 < end; a += 4) {
    float4 v0 = *(const float4*)&x[(size_t)a * DFEAT + fq * 4];
    float4 v1 = *(const float4*)&x[(size_t)(a + 2) * DFEAT + fq * 4];
    float xv0[4] = {v0.x, v0.y, v0.z, v0.w};
    float xv1[4] = {v1.x, v1.y, v1.z, v1.w};
#pragma unroll
    for (int q = 0; q < 4; ++q) {
      float den0 = fmaf(fmaf(C2, xv0[q], C1), xv0[q], C0);
      float den1 = fmaf(fmaf(C2, xv1[q], C1), xv1[q], C0);
      float r0 = __builtin_amdgcn_rcpf(den0);   // den <= -178 always
      float r1 = __builtin_amdgcn_rcpf(den1);
      float u0 = xv0[q] * r0;
      float u1 = xv1[q] * r1;
      Sr[q]  += r0 + r1;
      Sxr[q] += u0 + u1;
      Sxxr[q] = fmaf(xv0[q], u0, Sxxr[q]);
      Sxxr[q] = fmaf(xv1[q], u1, Sxxr[q]);
    }
  }
  for (; a < end; a += 2) {
    float4 v = *(const float4*)&x[(size_t)a * DFEAT + fq * 4];
    float xv[4] = {v.x, v.y, v.z, v.w};
#pragma unroll
    for (int q = 0; q < 4; ++q) {
      float den = fmaf(fmaf(C2, xv[q], C1), xv[q], C0);
      float r   = __builtin_amdgcn_rcpf(den);
      float u   = xv[q] * r;
      Sr[q]  += r;
      Sxr[q] += u;
      Sxxr[q] = fmaf(xv[q], u, Sxxr[q]);
    }
  }

  // Cross-half combine in-register: lane <-> lane^32 (no LDS, no barrier).
#pragma unroll
  for (int q = 0; q < 4; ++q) {
    Sr[q]   += __shfl_xor(Sr[q],   32, 64);
    Sxr[q]  += __shfl_xor(Sxr[q],  32, 64);
    Sxxr[q] += __shfl_xor(Sxxr[q], 32, 64);
  }

  if (h == 0) {   // lanes 0-31 hold the full molecule sums
    *(float4*)&As[w][fq * 4]             = make_float4(Sr[0],  Sr[1],  Sr[2],  Sr[3]);
    *(float4*)&As[w][DFEAT + fq * 4]     = make_float4(Sxr[0], Sxr[1], Sxr[2], Sxr[3]);
    *(float4*)&As[w][2 * DFEAT + fq * 4] = make_float4(Sxxr[0],Sxxr[1],Sxxr[2],Sxxr[3]);
  }
  __syncthreads();   // the ONLY phase-A/B barrier

  // ---------------- Phase B: [8 x 384] @ Bt[384 x 128], 4-way k-split ----
  const int n  = tid & 127;             // output column
  const int hh = tid >> 7;              // k-quarter 0..3 (uniform per wave)
  const int kbase = hh * (KDIM3 / 4);   // 0, 96, 192, 288

  float pacc[MPB];
#pragma unroll
  for (int i = 0; i < MPB; ++i) pacc[i] = 0.0f;

#pragma unroll 2
  for (int kk = 0; kk < KDIM3 / 4; kk += 4) {
    int k = kbase + kk;
    float b0 = Bt[(size_t)(k + 0) * N_DEPTH + n];
    float b1 = Bt[(size_t)(k + 1) * N_DEPTH + n];
    float b2 = Bt[(size_t)(k + 2) * N_DEPTH + n];
    float b3 = Bt[(size_t)(k + 3) * N_DEPTH + n];
#pragma unroll
    for (int i = 0; i < MPB; ++i) {
      float4 av = *(const float4*)&As[i][k];   // wave-uniform -> LDS broadcast
      pacc[i] = fmaf(av.x, b0, pacc[i]);
      pacc[i] = fmaf(av.y, b1, pacc[i]);
      pacc[i] = fmaf(av.z, b2, pacc[i]);
      pacc[i] = fmaf(av.w, b3, pacc[i]);
    }
  }

#pragma unroll
  for (int i = 0; i < MPB; ++i) comb[hh][i][n] = pacc[i];
  __syncthreads();

#pragma unroll
  for (int off = 0; off < (MPB * DFEAT) / TPB; ++off) {  // 2 iters
    int idx = off * TPB + tid;
    int i  = idx >> 7;
    int nn = idx & 127;
    float v = comb[0][i][nn] + comb[1][i][nn] + comb[2][i][nn] + comb[3][i][nn]
            + bias[nn];
    out[(size_t)(m0 + i) * N_DEPTH + nn] = tanhf(v);
  }
}

// ---------------------------------------------------------------------------
extern "C" void kernel_launch(void* const* d_in, const int* in_sizes, int n_in,
                              void* d_out, int out_size, void* d_ws, size_t ws_size,
                              hipStream_t stream) {
  const float* x     = (const float*)d_in[0];  // [131072, 128] f32
  const int*   split = (const int*)d_in[1];    // [131072] int (sorted)
  const float* W     = (const float*)d_in[2];  // [1408, 128] f32
  const float* bias  = (const float*)d_in[3];  // [128] f32
  float* out = (float*)d_out;                  // [4096, 128] f32

  // Workspace: Bt[384*128] f32 then offsets[4097] int (~213 KB total)
  float* Bt      = (float*)d_ws;
  int*   offsets = (int*)((char*)d_ws + (size_t)KDIM3 * N_DEPTH * 4);

  wxform_offsets_kernel<<<dim3(192 + 17), dim3(256), 0, stream>>>(W, split, Bt, offsets);
  fused_sums_gemm_kernel<<<dim3(N_MOLS / MPB), dim3(TPB), 0, stream>>>(x, offsets, Bt, bias, out);
}

// Round 8
// 112.671 us; speedup vs baseline: 1.6349x; 1.0061x over previous
//
#include <hip/hip_runtime.h>
#include <math.h>

#define N_ATOMS 131072
#define N_MOLS  4096
#define DFEAT   128
#define NK      11
#define KDIM3   384          // 3 * DFEAT: [Sr | Sxr | Sxxr] blocks
#define N_DEPTH 128
#define EPS_F   1e-7f
#define MPB     8            // molecules per block = waves per block
#define TPB     512
#define SCAN_BLOCKS (N_ATOMS / 256)   // 512

__constant__ float c_means[NK] = {-1.645f, -1.08f, -0.739f, -0.468f, -0.228f,
                                  0.0f, 0.228f, 0.468f, 0.739f, 1.08f, 1.645f};
__constant__ float c_stds[NK]  = {0.283f, 0.17f, 0.134f, 0.118f, 0.114f,
                                  0.114f, 0.114f, 0.118f, 0.134f, 0.17f, 0.283f};

// Math (verified passing, rounds 2/5/7):
//   o_k(x) = 1 + a_k (x - m_k)^2,  a_k = 0.5 / (s_k^2 * log(s_k*sqrt(2pi))) < 0
//   den(x) = sum_k o_k + EPS = C2 x^2 + C1 x + C0   (always <= -178, rcp-safe)
//   (o_k+EPS)/den = coef0(k)*r + coef1(k)*(x r) + coef2(k)*(x^2 r),  r = 1/den
//   => segment sum needs only Sr, Sxr, Sxxr per (mol, feature);
//      W folds into Bt[384][128] once per launch.

// ---------------------------------------------------------------------------
// Kernel 1: (a) blocks < 192: fold W into Bt[384][128];
//           (b) blocks >= 192: SCAN-based offsets (replaces 17-deep binary
//               search: 1 coalesced latency exposure instead of 17 serial).
//   offsets[j] = lower_bound(split, j). Thread per atom a:
//   writes offsets[j] = a for j in (split[a-1], split[a]]; last thread fills
//   the tail. Every j in [0, N_MOLS] is covered exactly once.
// ---------------------------------------------------------------------------
__global__ __launch_bounds__(256) void wxform_offsets_kernel(
    const float* __restrict__ W,        // [DFEAT*NK, N_DEPTH]
    const int*   __restrict__ split,    // [N_ATOMS], sorted
    float*       __restrict__ Bt,       // [KDIM3, N_DEPTH]
    int*         __restrict__ offsets) {// [N_MOLS+1]
  const int bid = blockIdx.x;
  const int tid = threadIdx.x;
  if (bid < 192) {
    int t = bid * 256 + tid;            // 0..49151
    int n = t & 127;
    int row = t >> 7;                   // 0..383
    int j = row >> 7;                   // 0..2 (uniform per wave)
    int d = row & 127;
    float acc = 0.0f;
#pragma unroll
    for (int k = 0; k < NK; ++k) {
      float m = c_means[k], s = c_stds[k];
      float a = 0.5f / (s * s * logf(s * 2.5066282746310002f));
      float coef = (j == 2) ? a
                 : (j == 1) ? (-2.0f * a * m)
                            : fmaf(a, m * m, 1.0f + EPS_F);
      acc = fmaf(coef, W[(size_t)(d * NK + k) * N_DEPTH + n], acc);
    }
    Bt[(size_t)row * N_DEPTH + n] = acc;
  } else {
    int a = (bid - 192) * 256 + tid;    // atom index 0..N_ATOMS-1
    int cur  = split[a];
    int prev = (a == 0) ? -1 : split[a - 1];
    for (int j = prev + 1; j <= cur; ++j) offsets[j] = a;
    if (a == N_ATOMS - 1)
      for (int j = cur + 1; j <= N_MOLS; ++j) offsets[j] = N_ATOMS;
  }
}

// ---------------------------------------------------------------------------
// Kernel 2 (fused): 512 threads = 8 waves; wave w owns molecule m0+w.
// Phase A: lanes 0-31 process even atoms, 32-63 odd atoms (one wave load =
//   2 contiguous x-rows = 1 KB, coalesced). x4 unroll -> 4 KB in flight per
//   wave. 12 register accumulators per lane; cross-half combine is 12 x
//   shfl_xor(32) in-register. No barriers, no LDS reduce, no spill.
//   __launch_bounds__(512, 8) pins VGPR <= 64 -> 4 blocks/CU = 32 waves/CU.
// Phase B: [8 x 384] @ Bt[384 x 128], 4-way k-split; each Bt element read
//   exactly once per block (512 blocks x 196 KB = 100 MB L2-resident).
// ---------------------------------------------------------------------------
__global__ __launch_bounds__(TPB, 8) void fused_sums_gemm_kernel(
    const float* __restrict__ x,        // [N_ATOMS, DFEAT]
    const int*   __restrict__ offsets,  // [N_MOLS+1]
    const float* __restrict__ Bt,       // [KDIM3, N_DEPTH]
    const float* __restrict__ bias,     // [N_DEPTH]
    float*       __restrict__ out) {    // [N_MOLS, N_DEPTH]
  const int tid = threadIdx.x;
  const int m0  = blockIdx.x * MPB;

  __shared__ float As[MPB][KDIM3];      // 12 KB
  __shared__ float comb[4][MPB][DFEAT]; // 16 KB

  // Horner coefficients for den = sum_k o_k + EPS (uniform, tiny)
  float C2 = 0.0f, C1 = 0.0f, C0 = 11.0f + EPS_F;
#pragma unroll
  for (int k = 0; k < NK; ++k) {
    float m_ = c_means[k], s_ = c_stds[k];
    float a = 0.5f / (s_ * s_ * logf(s_ * 2.5066282746310002f));
    C2 += a;
    C1 = fmaf(-2.0f * a, m_, C1);
    C0 = fmaf(a, m_ * m_, C0);
  }

  const int w    = tid >> 6;            // wave id = molecule slot 0..7
  const int lane = tid & 63;
  const int fq   = lane & 31;           // feature quad: features fq*4..fq*4+3
  const int h    = lane >> 5;           // atom parity 0/1

  const int start = offsets[m0 + w];
  const int end   = offsets[m0 + w + 1];

  // ---------------- Phase A: per-wave molecule sums ----------------
  float Sr[4]   = {0.f, 0.f, 0.f, 0.f};
  float Sxr[4]  = {0.f, 0.f, 0.f, 0.f};
  float Sxxr[4] = {0.f, 0.f, 0.f, 0.f};

  const float* xp = x + fq * 4;

  auto proc = [&](float4 v) {
    float xv[4] = {v.x, v.y, v.z, v.w};
#pragma unroll
    for (int q = 0; q < 4; ++q) {
      float den = fmaf(fmaf(C2, xv[q], C1), xv[q], C0);
      float r   = __builtin_amdgcn_rcpf(den);   // den <= -178 always
      float u   = xv[q] * r;
      Sr[q]  += r;
      Sxr[q] += u;
      Sxxr[q] = fmaf(xv[q], u, Sxxr[q]);
    }
  };

  int a = start + h;
  // x4 unroll: 4 wave-loads (4 KB) in flight
  for (; a + 6 < end; a += 8) {
    float4 v0 = *(const float4*)&xp[(size_t)(a + 0) * DFEAT];
    float4 v1 = *(const float4*)&xp[(size_t)(a + 2) * DFEAT];
    float4 v2 = *(const float4*)&xp[(size_t)(a + 4) * DFEAT];
    float4 v3 = *(const float4*)&xp[(size_t)(a + 6) * DFEAT];
    proc(v0); proc(v1); proc(v2); proc(v3);
  }
  for (; a < end; a += 2) {
    float4 v = *(const float4*)&xp[(size_t)a * DFEAT];
    proc(v);
  }

  // Cross-half combine in-register: lane <-> lane^32 (no LDS, no barrier).
#pragma unroll
  for (int q = 0; q < 4; ++q) {
    Sr[q]   += __shfl_xor(Sr[q],   32, 64);
    Sxr[q]  += __shfl_xor(Sxr[q],  32, 64);
    Sxxr[q] += __shfl_xor(Sxxr[q], 32, 64);
  }

  if (h == 0) {   // lanes 0-31 hold the full molecule sums
    *(float4*)&As[w][fq * 4]             = make_float4(Sr[0],  Sr[1],  Sr[2],  Sr[3]);
    *(float4*)&As[w][DFEAT + fq * 4]     = make_float4(Sxr[0], Sxr[1], Sxr[2], Sxr[3]);
    *(float4*)&As[w][2 * DFEAT + fq * 4] = make_float4(Sxxr[0],Sxxr[1],Sxxr[2],Sxxr[3]);
  }
  __syncthreads();   // the ONLY phase-A/B barrier

  // ---------------- Phase B: [8 x 384] @ Bt[384 x 128], 4-way k-split ----
  const int n  = tid & 127;             // output column
  const int hh = tid >> 7;              // k-quarter 0..3 (uniform per wave)
  const int kbase = hh * (KDIM3 / 4);   // 0, 96, 192, 288

  float pacc[MPB];
#pragma unroll
  for (int i = 0; i < MPB; ++i) pacc[i] = 0.0f;

#pragma unroll 2
  for (int kk = 0; kk < KDIM3 / 4; kk += 4) {
    int k = kbase + kk;
    float b0 = Bt[(size_t)(k + 0) * N_DEPTH + n];
    float b1 = Bt[(size_t)(k + 1) * N_DEPTH + n];
    float b2 = Bt[(size_t)(k + 2) * N_DEPTH + n];
    float b3 = Bt[(size_t)(k + 3) * N_DEPTH + n];
#pragma unroll
    for (int i = 0; i < MPB; ++i) {
      float4 av = *(const float4*)&As[i][k];   // wave-uniform -> LDS broadcast
      pacc[i] = fmaf(av.x, b0, pacc[i]);
      pacc[i] = fmaf(av.y, b1, pacc[i]);
      pacc[i] = fmaf(av.z, b2, pacc[i]);
      pacc[i] = fmaf(av.w, b3, pacc[i]);
    }
  }

#pragma unroll
  for (int i = 0; i < MPB; ++i) comb[hh][i][n] = pacc[i];
  __syncthreads();

#pragma unroll
  for (int off = 0; off < (MPB * DFEAT) / TPB; ++off) {  // 2 iters
    int idx = off * TPB + tid;
    int i  = idx >> 7;
    int nn = idx & 127;
    float v = comb[0][i][nn] + comb[1][i][nn] + comb[2][i][nn] + comb[3][i][nn]
            + bias[nn];
    out[(size_t)(m0 + i) * N_DEPTH + nn] = tanhf(v);
  }
}

// ---------------------------------------------------------------------------
extern "C" void kernel_launch(void* const* d_in, const int* in_sizes, int n_in,
                              void* d_out, int out_size, void* d_ws, size_t ws_size,
                              hipStream_t stream) {
  const float* x     = (const float*)d_in[0];  // [131072, 128] f32
  const int*   split = (const int*)d_in[1];    // [131072] int (sorted)
  const float* W     = (const float*)d_in[2];  // [1408, 128] f32
  const float* bias  = (const float*)d_in[3];  // [128] f32
  float* out = (float*)d_out;                  // [4096, 128] f32

  // Workspace: Bt[384*128] f32 then offsets[4097] int (~213 KB total)
  float* Bt      = (float*)d_ws;
  int*   offsets = (int*)((char*)d_ws + (size_t)KDIM3 * N_DEPTH * 4);

  wxform_offsets_kernel<<<dim3(192 + SCAN_BLOCKS), dim3(256), 0, stream>>>(W, split, Bt, offsets);
  fused_sums_gemm_kernel<<<dim3(N_MOLS / MPB), dim3(TPB), 0, stream>>>(x, offsets, Bt, bias, out);
}